// Round 2
// baseline (672.274 us; speedup 1.0000x reference)
//
#include <hip/hip_runtime.h>
#include <hip/hip_bf16.h>

// ModulatedConv2d: B=8, CIN=32, COUT=32, K=3, H=W=512, MAPPING_DIM=1024
// Two-pass design:
//   prep: style GEMV + per-sample modulated weight fragments (MFMA B layout)
//   xt:   NCHW fp32 -> NHWC bf16 (register transpose, pure streaming, no LDS)
//   conv: LDS-free MFMA conv; A-fragments load directly from NHWC xt as one
//         coalesced 1KB wave access; 9x reuse via L1/L2. No barriers.
// xt placement is runtime-tiered on ws_size; tier-2 packs xt into the out
// tail with a hazard-free dispatch order (see kernel_launch).

typedef short  short8 __attribute__((ext_vector_type(8)));
typedef float  f32x4  __attribute__((ext_vector_type(4)));

struct XtBases { unsigned short* p[8]; };

static __device__ inline unsigned short f2bf(float f) {
    unsigned int u = __float_as_uint(f);
    unsigned int r = (u + 0x7fffu + ((u >> 16) & 1u)) >> 16;   // RNE
    return (unsigned short)r;
}

// style[b][ci] = w[b]·sw[ci] + sb[ci]; wfrag[b][off][half][lane][j] =
// kern[cout=half*16+(lane&15)][cin=(lane>>4)*8+j][kh][kw] * style[b][cin]
__global__ __launch_bounds__(256) void prep_kernel(const float* __restrict__ w,
                                                   const float* __restrict__ sw,
                                                   const float* __restrict__ sb,
                                                   const float* __restrict__ kern,
                                                   unsigned short* __restrict__ wfrag) {
    __shared__ float sstyle[32];
    const int b = blockIdx.x;
    const int t = threadIdx.x, lane = t & 63, wave = t >> 6;
    const float* wp = w + b * 1024;
    #pragma unroll
    for (int i = 0; i < 8; ++i) {
        const int ci = wave * 8 + i;
        const float* sp = sw + ci * 1024;
        float s = 0.f;
        #pragma unroll
        for (int k = 0; k < 16; ++k) s += wp[lane + 64 * k] * sp[lane + 64 * k];
        #pragma unroll
        for (int off = 32; off; off >>= 1) s += __shfl_down(s, off, 64);
        if (lane == 0) sstyle[ci] = s + sb[ci];
    }
    __syncthreads();
    unsigned short* wfb = wfrag + b * 9216;
    #pragma unroll
    for (int k = 0; k < 36; ++k) {
        const int f = t + 256 * k;                 // 36*256 = 9216 exactly
        const int off = f >> 10, r2 = f & 1023;
        const int half = r2 >> 9, ln = (r2 >> 3) & 63, j = r2 & 7;
        const int cout = half * 16 + (ln & 15);
        const int cin  = (ln >> 4) * 8 + j;
        const int kh = off / 3, kw = off % 3;
        wfb[f] = f2bf(kern[(cout * 32 + cin) * 9 + kh * 3 + kw] * sstyle[cin]);
    }
}

// xt[b][h][w][cin] = bf16(x[b][cin][h][w]).  Block: one (b,h,256-px chunk).
// Thread: 8 coalesced f32x4 loads (cins c8*8..+7, 4 px) -> register transpose
// -> 4 x 16B global writes (8 cins of one pixel each).
__global__ __launch_bounds__(256) void xt_kernel(const float* __restrict__ x, XtBases xb) {
    const int b  = blockIdx.z;
    const int h  = blockIdx.y;
    const int w0 = blockIdx.x * 256;
    const int t   = threadIdx.x;
    const int px4 = t & 63;          // 64 chunks of 4 px
    const int c8  = t >> 6;          // 0..3 -> cins c8*8..+7
    const float* xp = x + (size_t)b * 8388608 + h * 512 + (w0 + px4 * 4);
    f32x4 v[8];
    #pragma unroll
    for (int j = 0; j < 8; ++j)
        v[j] = *(const f32x4*)(xp + (size_t)(c8 * 8 + j) * 262144);
    unsigned short* o = xb.p[b] + ((size_t)(h * 512 + w0 + px4 * 4) * 32 + c8 * 8);
    #pragma unroll
    for (int e = 0; e < 4; ++e) {
        uint4 d;
        __hip_bfloat162 h0 = __float22bfloat162_rn(make_float2(v[0][e], v[1][e]));
        __hip_bfloat162 h1 = __float22bfloat162_rn(make_float2(v[2][e], v[3][e]));
        __hip_bfloat162 h2 = __float22bfloat162_rn(make_float2(v[4][e], v[5][e]));
        __hip_bfloat162 h3 = __float22bfloat162_rn(make_float2(v[6][e], v[7][e]));
        d.x = *(unsigned int*)&h0; d.y = *(unsigned int*)&h1;
        d.z = *(unsigned int*)&h2; d.w = *(unsigned int*)&h3;
        *(uint4*)(o + e * 32) = d;
    }
}

// LDS-free conv. Block 256 thr = 4 waves; tile 4 rows x 32 px x 32 cout.
// wave: hf = cout half, rp = row pair. Per c16 group: 4 row-windows, each
// window's 3 kw-fragments feed both output rows (24 loads / 36 MFMA / task).
__global__ __launch_bounds__(256, 4) void conv_kernel(XtBases xb,
                                                      const unsigned short* __restrict__ wfrag,
                                                      float* __restrict__ out, int b0) {
    const int b  = b0 + blockIdx.z;
    const int h0 = blockIdx.y * 4;
    const int w0 = blockIdx.x * 32;
    const int t = threadIdx.x, lane = t & 63, wave = t >> 6;
    const int hf = wave & 1, rp = wave >> 1;
    const int n = lane & 15, kg = lane >> 4;

    // weight fragments for this wave's cout half: 9 x short8 = 36 VGPRs
    short8 wreg[9];
    {
        const unsigned short* wf = wfrag + b * 9216;
        #pragma unroll
        for (int off = 0; off < 9; ++off)
            wreg[off] = *(const short8*)(wf + ((off * 2 + hf) * 64 + lane) * 8);
    }

    const unsigned short* xt = xb.p[b];
    float* ob = out + (size_t)b * 8388608;
    const int r0 = h0 + rp * 2;          // acc0 output row; acc1 = r0+1

    #pragma unroll
    for (int cg = 0; cg < 2; ++cg) {
        const int c16 = cg * 16;
        f32x4 acc0 = {0.f, 0.f, 0.f, 0.f};
        f32x4 acc1 = {0.f, 0.f, 0.f, 0.f};
        #pragma unroll
        for (int rw = 0; rw < 4; ++rw) {           // xt row window r0-1 .. r0+2
            const int grw = r0 + rw - 1;
            if ((unsigned)grw < 512u) {            // wave-uniform row guard
                short8 f[3];
                #pragma unroll
                for (int kw = 0; kw < 3; ++kw) {
                    const int gwf = w0 + c16 + kw - 1;   // + n per-lane pixel
                    f[kw] = *(const short8*)(xt + ((grw * 512 + gwf + n) * 32 + kg * 8));
                    // column zero-pad: only the two edge block columns
                    if ((w0 == 0 && c16 == 0 && kw == 0) ||
                        (w0 == 480 && c16 == 16 && kw == 2)) {
                        if ((unsigned)(gwf + n) >= 512u)
                            f[kw] = (short8){0, 0, 0, 0, 0, 0, 0, 0};
                    }
                }
                #pragma unroll
                for (int kw = 0; kw < 3; ++kw) {
                    if (rw <= 2)   // acc0 row r0: kh = rw
                        acc0 = __builtin_amdgcn_mfma_f32_16x16x32_bf16(
                                   f[kw], wreg[rw * 3 + kw], acc0, 0, 0, 0);
                    if (rw >= 1)   // acc1 row r0+1: kh = rw-1
                        acc1 = __builtin_amdgcn_mfma_f32_16x16x32_bf16(
                                   f[kw], wreg[(rw - 1) * 3 + kw], acc1, 0, 0, 0);
                }
            }
        }
        // C/D: col = lane&15 = cout(within half), rows kg*4+reg = 4 consecutive px
        float* p0 = ob + (size_t)(hf * 16 + n) * 262144 + r0 * 512 + (w0 + c16 + kg * 4);
        *(f32x4*)p0 = acc0;
        *(f32x4*)(p0 + 512) = acc1;
    }
}

extern "C" void kernel_launch(void* const* d_in, const int* in_sizes, int n_in,
                              void* d_out, int out_size, void* d_ws, size_t ws_size,
                              hipStream_t stream) {
    const float* x    = (const float*)d_in[0];   // [8,32,512,512]
    const float* w    = (const float*)d_in[1];   // [8,1024]
    const float* kern = (const float*)d_in[2];   // [32,32,3,3]
    const float* sw   = (const float*)d_in[3];   // [32,1024]
    const float* sb   = (const float*)d_in[4];   // [32]
    float* out = (float*)d_out;                  // [8,32,512,512] fp32

    unsigned short* wfrag = (unsigned short*)d_ws;       // [0, 147456)
    const size_t IMG = 16777216;                         // xt bytes per image
    const size_t XT0 = 147520;                           // wfrag + 64B guard
    char* wsp = (char*)d_ws;
    char* op  = (char*)d_out;

    const bool tier1 = ws_size >= XT0 + 8 * IMG + 128;
    XtBases xb;
    if (tier1) {
        for (int b = 0; b < 8; ++b)
            xb.p[b] = (unsigned short*)(wsp + XT0 + (size_t)b * IMG);
    } else {
        // xt[0..6] packed into out[4..7] region; xt[7] in ws (16.8 MB).
        // Hazard-free order: conv(b0-3) -> conv(b4) -> conv(b5) -> conv(b6)
        // -> conv(b7): each dispatch's out-writes cover only already-dead xt.
        for (int b = 0; b < 7; ++b)
            xb.p[b] = (unsigned short*)(op + 134217728 + (size_t)b * IMG);
        xb.p[7] = (unsigned short*)(wsp + XT0);
    }

    prep_kernel<<<8, 256, 0, stream>>>(w, sw, sb, kern, wfrag);
    xt_kernel<<<dim3(2, 512, 8), 256, 0, stream>>>(x, xb);
    if (tier1) {
        conv_kernel<<<dim3(16, 128, 8), 256, 0, stream>>>(xb, wfrag, out, 0);
    } else {
        conv_kernel<<<dim3(16, 128, 4), 256, 0, stream>>>(xb, wfrag, out, 0);
        conv_kernel<<<dim3(16, 128, 1), 256, 0, stream>>>(xb, wfrag, out, 4);
        conv_kernel<<<dim3(16, 128, 1), 256, 0, stream>>>(xb, wfrag, out, 5);
        conv_kernel<<<dim3(16, 128, 1), 256, 0, stream>>>(xb, wfrag, out, 6);
        conv_kernel<<<dim3(16, 128, 1), 256, 0, stream>>>(xb, wfrag, out, 7);
    }
}